// Round 1
// baseline (431.885 us; speedup 1.0000x reference)
//
#include <hip/hip_runtime.h>

#define IN_F 128

// ---------------- degree / CSR construction ----------------

__global__ void k_init_cnt(int* cnt, int n) {
    int i = blockIdx.x * blockDim.x + threadIdx.x;
    if (i < n) cnt[i] = 1;  // self-loop
}

__global__ void k_count(const int* __restrict__ dst, int* cnt, int E) {
    int e = blockIdx.x * blockDim.x + threadIdx.x;
    if (e < E) atomicAdd(&cnt[dst[e]], 1);
}

__global__ void k_dis(const int* __restrict__ cnt, float* __restrict__ dis, int n) {
    int i = blockIdx.x * blockDim.x + threadIdx.x;
    if (i < n) dis[i] = rsqrtf((float)cnt[i]);
}

// exclusive prefix sum over cnt[0..n) -> row_ptr[0..n], single block of 1024
__global__ __launch_bounds__(1024) void k_scan(const int* __restrict__ cnt,
                                               int* __restrict__ row_ptr, int n) {
    __shared__ int sdat[1024];
    __shared__ int s_carry;
    int tid = threadIdx.x;
    if (tid == 0) s_carry = 0;
    __syncthreads();
    for (int base = 0; base < n; base += 1024) {
        int i = base + tid;
        int v = (i < n) ? cnt[i] : 0;
        sdat[tid] = v;
        __syncthreads();
        for (int off = 1; off < 1024; off <<= 1) {
            int t = (tid >= off) ? sdat[tid - off] : 0;
            __syncthreads();
            sdat[tid] += t;
            __syncthreads();
        }
        int incl = sdat[tid];
        if (i < n) row_ptr[i] = s_carry + incl - v;
        int tot = sdat[1023];
        __syncthreads();
        if (tid == 0) s_carry += tot;
        __syncthreads();
    }
    if (tid == 0) row_ptr[n] = s_carry;
}

__global__ void k_copy(const int* __restrict__ src, int* __restrict__ dstp, int n) {
    int i = blockIdx.x * blockDim.x + threadIdx.x;
    if (i < n) dstp[i] = src[i];
}

__global__ void k_fill(const int* __restrict__ ei, const float* __restrict__ dis,
                       int* fill_pos, int* __restrict__ es, float* __restrict__ en,
                       int E, int n) {
    int t = blockIdx.x * blockDim.x + threadIdx.x;
    int total = E + n;
    if (t >= total) return;
    int s, d;
    if (t < E) { s = ei[t]; d = ei[E + t]; }
    else       { s = t - E; d = s; }
    int p = atomicAdd(&fill_pos[d], 1);
    es[p] = s;
    en[p] = dis[s] * dis[d];
}

// ---------------- dense GEMM: Y[n,M] = X[n,128] @ W[128,M] ----------------

template<int M>
__global__ __launch_bounds__(256) void k_gemm(const float* __restrict__ X,
                                              const float* __restrict__ W,
                                              float* __restrict__ Y, int n) {
    constexpr int K  = 128;
    constexpr int CG = M / 4;     // float4 column-groups
    constexpr int RP = 256 / CG;  // rows per pass
    __shared__ float wlds[K * M];
    __shared__ float xs[RP][K + 1];
    for (int idx = threadIdx.x; idx < K * M; idx += 256) wlds[idx] = W[idx];
    const int cg = threadIdx.x % CG;
    const int r  = threadIdx.x / CG;
    for (int base = blockIdx.x * RP; base < n; base += gridDim.x * RP) {
        __syncthreads();  // also covers initial wlds load
        for (int idx = threadIdx.x; idx < RP * (K / 4); idx += 256) {
            int rr = idx / (K / 4);
            int cc = idx % (K / 4);
            int row = base + rr;
            float4 v = make_float4(0.f, 0.f, 0.f, 0.f);
            if (row < n) v = *(const float4*)(X + (size_t)row * K + cc * 4);
            xs[rr][cc * 4 + 0] = v.x; xs[rr][cc * 4 + 1] = v.y;
            xs[rr][cc * 4 + 2] = v.z; xs[rr][cc * 4 + 3] = v.w;
        }
        __syncthreads();
        int row = base + r;
        float ax = 0.f, ay = 0.f, az = 0.f, aw = 0.f;
#pragma unroll 8
        for (int k = 0; k < K; ++k) {
            float xv = xs[r][k];
            const float4 w4 = *(const float4*)(&wlds[k * M + cg * 4]);
            ax += xv * w4.x; ay += xv * w4.y; az += xv * w4.z; aw += xv * w4.w;
        }
        if (row < n) {
            *(float4*)(Y + (size_t)row * M + cg * 4) = make_float4(ax, ay, az, aw);
        }
    }
}

// ---------------- CSR aggregation: out[d] = sum_e norm_e * h[src_e] (+bias, relu) ----

template<int F, bool RELU>
__global__ __launch_bounds__(256) void k_agg(const float* __restrict__ h,
                                             const int* __restrict__ row_ptr,
                                             const int* __restrict__ es,
                                             const float* __restrict__ en,
                                             const float* __restrict__ bias,
                                             float* __restrict__ out, int n) {
    int node = blockIdx.x * 4 + (threadIdx.x >> 6);
    if (node >= n) return;
    int lane = threadIdx.x & 63;
    int beg = row_ptr[node], end = row_ptr[node + 1];
    if (F == 128) {
        float ax = 0.f, ay = 0.f;
        for (int e = beg; e < end; ++e) {
            int s = es[e];
            float wgt = en[e];
            const float2 v = *(const float2*)(h + (size_t)s * 128 + lane * 2);
            ax += wgt * v.x; ay += wgt * v.y;
        }
        ax += bias[lane * 2]; ay += bias[lane * 2 + 1];
        if (RELU) { ax = fmaxf(ax, 0.f); ay = fmaxf(ay, 0.f); }
        *(float2*)(out + (size_t)node * 128 + lane * 2) = make_float2(ax, ay);
    } else {
        float a = 0.f;
        for (int e = beg; e < end; ++e) {
            int s = es[e];
            float wgt = en[e];
            a += wgt * h[(size_t)s * 64 + lane];
        }
        a += bias[lane];
        if (RELU) a = fmaxf(a, 0.f);
        out[(size_t)node * 64 + lane] = a;
    }
}

// ---------------- launch ----------------

extern "C" void kernel_launch(void* const* d_in, const int* in_sizes, int n_in,
                              void* d_out, int out_size, void* d_ws, size_t ws_size,
                              hipStream_t stream) {
    const float* x  = (const float*)d_in[0];
    const int*   ei = (const int*)d_in[1];
    const float* W1 = (const float*)d_in[2];
    const float* b1 = (const float*)d_in[3];
    const float* W2 = (const float*)d_in[4];
    const float* b2 = (const float*)d_in[5];
    float* out = (float*)d_out;

    const int n  = in_sizes[0] / IN_F;
    const int E  = in_sizes[1] / 2;
    const int EN = E + n;

    char* w = (char*)d_ws;
    int*   cnt      = (int*)w;   w += (size_t)n * 4;
    int*   row_ptr  = (int*)w;   w += (size_t)(n + 4) * 4;  // padded for 16B alignment
    int*   fill_pos = (int*)w;   w += (size_t)n * 4;
    float* dis      = (float*)w; w += (size_t)n * 4;
    int*   es       = (int*)w;   w += (size_t)EN * 4;
    float* en       = (float*)w; w += (size_t)EN * 4;
    float* h1       = (float*)w; w += (size_t)n * 128 * 4;
    float* a1       = (float*)w; w += (size_t)n * 128 * 4;
    float* h2       = h1;  // reuse: h1 dead after first aggregation

    const int nbN = (n + 255) / 256;
    k_init_cnt<<<nbN, 256, 0, stream>>>(cnt, n);
    k_count<<<(E + 255) / 256, 256, 0, stream>>>(ei + E, cnt, E);
    k_dis<<<nbN, 256, 0, stream>>>(cnt, dis, n);
    k_scan<<<1, 1024, 0, stream>>>(cnt, row_ptr, n);
    k_copy<<<nbN, 256, 0, stream>>>(row_ptr, fill_pos, n);
    k_fill<<<(EN + 255) / 256, 256, 0, stream>>>(ei, dis, fill_pos, es, en, E, n);

    k_gemm<128><<<1024, 256, 0, stream>>>(x, W1, h1, n);
    k_agg<128, true><<<(n + 3) / 4, 256, 0, stream>>>(h1, row_ptr, es, en, b1, a1, n);
    k_gemm<64><<<1024, 256, 0, stream>>>(a1, W2, h2, n);
    k_agg<64, false><<<(n + 3) / 4, 256, 0, stream>>>(h2, row_ptr, es, en, b2, out, n);
}

// Round 3
// 276.519 us; speedup vs baseline: 1.5619x; 1.5619x over previous
//
#include <hip/hip_runtime.h>

typedef unsigned short u16;

#define IN_F 128

// ---------- helpers ----------
__device__ inline float bf2f(u16 v) {
    return __uint_as_float(((unsigned)v) << 16);
}
__device__ inline u16 f2bf(float f) {
    unsigned u = __float_as_uint(f);
    unsigned r = (u + 0x7fffu + ((u >> 16) & 1u)) >> 16;
    return (u16)r;
}

// ---------------- degree / CSR construction ----------------

__global__ void k_init_cnt(int* cnt, int n) {
    int i = blockIdx.x * blockDim.x + threadIdx.x;
    if (i < n) cnt[i] = 1;  // self-loop
}

__global__ void k_count(const int* __restrict__ dst, int* cnt, int E) {
    int e = blockIdx.x * blockDim.x + threadIdx.x;
    if (e < E) atomicAdd(&cnt[dst[e]], 1);
}

// block-wide exclusive scan helper (256 threads); sdat[255] holds block total after call
__device__ inline int block_scan_excl(int v, int* sdat) {
    int tid = threadIdx.x;
    sdat[tid] = v;
    __syncthreads();
#pragma unroll
    for (int off = 1; off < 256; off <<= 1) {
        int t = (tid >= off) ? sdat[tid - off] : 0;
        __syncthreads();
        sdat[tid] += t;
        __syncthreads();
    }
    return sdat[tid] - v;
}

// phase 1: per-block totals
__global__ __launch_bounds__(256) void k_scan1(const int* __restrict__ cnt,
                                               int* __restrict__ bsum, int n) {
    __shared__ int sdat[256];
    int i = blockIdx.x * 256 + threadIdx.x;
    int v = (i < n) ? cnt[i] : 0;
    (void)block_scan_excl(v, sdat);
    if (threadIdx.x == 0) bsum[blockIdx.x] = sdat[255];
}

// phase 2: single block scans the block totals (nb <= 1024)
__global__ __launch_bounds__(1024) void k_scan2(const int* __restrict__ bsum,
                                                int* __restrict__ boffs,
                                                int* __restrict__ row_ptr,
                                                int nb, int n) {
    __shared__ int sdat[1024];
    int tid = threadIdx.x;
    int v = (tid < nb) ? bsum[tid] : 0;
    sdat[tid] = v;
    __syncthreads();
#pragma unroll
    for (int off = 1; off < 1024; off <<= 1) {
        int t = (tid >= off) ? sdat[tid - off] : 0;
        __syncthreads();
        sdat[tid] += t;
        __syncthreads();
    }
    if (tid < nb) boffs[tid] = sdat[tid] - v;
    if (tid == 0) row_ptr[n] = sdat[1023];
}

// phase 3: per-block exclusive scan + block offset -> row_ptr and fill_pos
__global__ __launch_bounds__(256) void k_scan3(const int* __restrict__ cnt,
                                               const int* __restrict__ boffs,
                                               int* __restrict__ row_ptr,
                                               int* __restrict__ fill_pos, int n) {
    __shared__ int sdat[256];
    int i = blockIdx.x * 256 + threadIdx.x;
    int v = (i < n) ? cnt[i] : 0;
    int ex = block_scan_excl(v, sdat);
    if (i < n) {
        int rp = boffs[blockIdx.x] + ex;
        row_ptr[i] = rp;
        fill_pos[i] = rp;
    }
}

// edge records: {src, norm_bits} packed as int2
__global__ void k_fill(const int* __restrict__ ei, const int* __restrict__ cnt,
                       int* fill_pos, int2* __restrict__ er, int E, int n) {
    int t = blockIdx.x * blockDim.x + threadIdx.x;
    int total = E + n;
    if (t >= total) return;
    int s, d;
    if (t < E) { s = ei[t]; d = ei[E + t]; }
    else       { s = t - E; d = s; }
    float nrm = rsqrtf((float)cnt[s]) * rsqrtf((float)cnt[d]);
    int p = atomicAdd(&fill_pos[d], 1);
    er[p] = make_int2(s, __float_as_int(nrm));
}

// ---------------- dense GEMM: Y[n,M](bf16) = X[n,128](f32) @ W[128,M](f32) ----------

template<int M>
__global__ __launch_bounds__(256) void k_gemm(const float* __restrict__ X,
                                              const float* __restrict__ W,
                                              u16* __restrict__ Y, int n) {
    constexpr int K  = 128;
    constexpr int CG = M / 4;     // float4 column-groups
    constexpr int RP = 256 / CG;  // rows per pass
    __shared__ float wlds[K * M];
    __shared__ float xs[RP][K + 1];
    for (int idx = threadIdx.x; idx < K * M; idx += 256) wlds[idx] = W[idx];
    const int cg = threadIdx.x % CG;
    const int r  = threadIdx.x / CG;
    for (int base = blockIdx.x * RP; base < n; base += gridDim.x * RP) {
        __syncthreads();  // also covers initial wlds load
        for (int idx = threadIdx.x; idx < RP * (K / 4); idx += 256) {
            int rr = idx / (K / 4);
            int cc = idx % (K / 4);
            int row = base + rr;
            float4 v = make_float4(0.f, 0.f, 0.f, 0.f);
            if (row < n) v = *(const float4*)(X + (size_t)row * K + cc * 4);
            xs[rr][cc * 4 + 0] = v.x; xs[rr][cc * 4 + 1] = v.y;
            xs[rr][cc * 4 + 2] = v.z; xs[rr][cc * 4 + 3] = v.w;
        }
        __syncthreads();
        int row = base + r;
        float ax = 0.f, ay = 0.f, az = 0.f, aw = 0.f;
#pragma unroll 8
        for (int k = 0; k < K; ++k) {
            float xv = xs[r][k];
            const float4 w4 = *(const float4*)(&wlds[k * M + cg * 4]);
            ax += xv * w4.x; ay += xv * w4.y; az += xv * w4.z; aw += xv * w4.w;
        }
        if (row < n) {
            ushort4 o;
            o.x = f2bf(ax); o.y = f2bf(ay); o.z = f2bf(az); o.w = f2bf(aw);
            *(ushort4*)(Y + (size_t)row * M + cg * 4) = o;
        }
    }
}

// ------- CSR aggregation: out[d] = sum_e norm_e * h_bf16[src_e] (+bias, relu) -------

template<int F, bool RELU>
__global__ __launch_bounds__(256) void k_agg(const u16* __restrict__ h,
                                             const int* __restrict__ row_ptr,
                                             const int2* __restrict__ er,
                                             const float* __restrict__ bias,
                                             float* __restrict__ out, int n) {
    int node = blockIdx.x * 4 + (threadIdx.x >> 6);
    if (node >= n) return;
    int lane = threadIdx.x & 63;
    int beg = row_ptr[node], end = row_ptr[node + 1];
    if (F == 128) {
        const u16* hp = h + lane * 2;
        float ax = 0.f, ay = 0.f, bx = 0.f, by = 0.f;
        int e = beg;
        for (; e + 1 < end; e += 2) {
            int2 r0 = er[e], r1 = er[e + 1];
            float w0 = __int_as_float(r0.y);
            float w1 = __int_as_float(r1.y);
            ushort2 v0 = *(const ushort2*)(hp + (size_t)r0.x * 128);
            ushort2 v1 = *(const ushort2*)(hp + (size_t)r1.x * 128);
            ax += w0 * bf2f(v0.x); ay += w0 * bf2f(v0.y);
            bx += w1 * bf2f(v1.x); by += w1 * bf2f(v1.y);
        }
        if (e < end) {
            int2 r0 = er[e];
            float w0 = __int_as_float(r0.y);
            ushort2 v0 = *(const ushort2*)(hp + (size_t)r0.x * 128);
            ax += w0 * bf2f(v0.x); ay += w0 * bf2f(v0.y);
        }
        ax += bx; ay += by;
        ax += bias[lane * 2]; ay += bias[lane * 2 + 1];
        if (RELU) { ax = fmaxf(ax, 0.f); ay = fmaxf(ay, 0.f); }
        *(float2*)(out + (size_t)node * 128 + lane * 2) = make_float2(ax, ay);
    } else {
        const u16* hp = h + lane;
        float a = 0.f, b = 0.f;
        int e = beg;
        for (; e + 1 < end; e += 2) {
            int2 r0 = er[e], r1 = er[e + 1];
            float w0 = __int_as_float(r0.y);
            float w1 = __int_as_float(r1.y);
            u16 v0 = hp[(size_t)r0.x * 64];
            u16 v1 = hp[(size_t)r1.x * 64];
            a += w0 * bf2f(v0);
            b += w1 * bf2f(v1);
        }
        if (e < end) {
            int2 r0 = er[e];
            a += __int_as_float(r0.y) * bf2f(hp[(size_t)r0.x * 64]);
        }
        a += b;
        a += bias[lane];
        if (RELU) a = fmaxf(a, 0.f);
        out[(size_t)node * 64 + lane] = a;
    }
}

// ---------------- launch ----------------

static inline char* alignp(char* p, size_t a) {
    return (char*)(((uintptr_t)p + a - 1) & ~(uintptr_t)(a - 1));
}

extern "C" void kernel_launch(void* const* d_in, const int* in_sizes, int n_in,
                              void* d_out, int out_size, void* d_ws, size_t ws_size,
                              hipStream_t stream) {
    const float* x  = (const float*)d_in[0];
    const int*   ei = (const int*)d_in[1];
    const float* W1 = (const float*)d_in[2];
    const float* b1 = (const float*)d_in[3];
    const float* W2 = (const float*)d_in[4];
    const float* b2 = (const float*)d_in[5];
    float* out = (float*)d_out;

    const int n  = in_sizes[0] / IN_F;
    const int E  = in_sizes[1] / 2;
    const int EN = E + n;
    const int nb = (n + 255) / 256;

    char* w = (char*)d_ws;
    int*   cnt      = (int*)w;   w = alignp(w + (size_t)n * 4, 256);
    int*   row_ptr  = (int*)w;   w = alignp(w + (size_t)(n + 1) * 4, 256);
    int*   fill_pos = (int*)w;   w = alignp(w + (size_t)n * 4, 256);
    int*   bsum     = (int*)w;   w = alignp(w + (size_t)nb * 4, 256);
    int*   boffs    = (int*)w;   w = alignp(w + (size_t)nb * 4, 256);
    int2*  er       = (int2*)w;  w = alignp(w + (size_t)EN * 8, 256);
    u16*   h1b      = (u16*)w;   w = alignp(w + (size_t)n * 128 * 2, 256);
    float* a1       = (float*)w; w = alignp(w + (size_t)n * 128 * 4, 256);
    u16*   h2b      = h1b;  // reuse: h1b dead after first aggregation (64<=128 cols)

    k_init_cnt<<<nb, 256, 0, stream>>>(cnt, n);
    k_count<<<(E + 255) / 256, 256, 0, stream>>>(ei + E, cnt, E);
    k_scan1<<<nb, 256, 0, stream>>>(cnt, bsum, n);
    k_scan2<<<1, 1024, 0, stream>>>(bsum, boffs, row_ptr, nb, n);
    k_scan3<<<nb, 256, 0, stream>>>(cnt, boffs, row_ptr, fill_pos, n);
    k_fill<<<(EN + 255) / 256, 256, 0, stream>>>(ei, cnt, fill_pos, er, E, n);

    k_gemm<128><<<1024, 256, 0, stream>>>(x, W1, h1b, n);
    k_agg<128, true><<<(n + 3) / 4, 256, 0, stream>>>(h1b, row_ptr, er, b1, a1, n);
    k_gemm<64><<<1024, 256, 0, stream>>>(a1, W2, h2b, n);
    k_agg<64, false><<<(n + 3) / 4, 256, 0, stream>>>(h2b, row_ptr, er, b2, out, n);
}

// Round 4
// 212.097 us; speedup vs baseline: 2.0363x; 1.3037x over previous
//
#include <hip/hip_runtime.h>

typedef unsigned short u16;
typedef __attribute__((ext_vector_type(8))) short bf16x8;
typedef __attribute__((ext_vector_type(4))) float f32x4;
typedef __attribute__((ext_vector_type(2))) float f32x2;

#define IN_F 128

// ---------- helpers ----------
__device__ inline float bf2f(u16 v) {
    return __uint_as_float(((unsigned)v) << 16);
}
__device__ inline u16 f2bf(float f) {
    unsigned u = __float_as_uint(f);
    return (u16)((u + 0x7fffu + ((u >> 16) & 1u)) >> 16);
}

// ---------------- degree / CSR construction ----------------

__global__ void k_init_cnt(int* cnt, int n) {
    int i = blockIdx.x * blockDim.x + threadIdx.x;
    if (i < n) cnt[i] = 1;  // self-loop
}

__global__ void k_count(const int* __restrict__ dst, int* cnt, int E) {
    int e = blockIdx.x * blockDim.x + threadIdx.x;
    if (e < E) atomicAdd(&cnt[dst[e]], 1);
}

__device__ inline int block_scan_excl(int v, int* sdat) {
    int tid = threadIdx.x;
    sdat[tid] = v;
    __syncthreads();
#pragma unroll
    for (int off = 1; off < 256; off <<= 1) {
        int t = (tid >= off) ? sdat[tid - off] : 0;
        __syncthreads();
        sdat[tid] += t;
        __syncthreads();
    }
    return sdat[tid] - v;
}

__global__ __launch_bounds__(256) void k_scan1(const int* __restrict__ cnt,
                                               int* __restrict__ bsum, int n) {
    __shared__ int sdat[256];
    int i = blockIdx.x * 256 + threadIdx.x;
    int v = (i < n) ? cnt[i] : 0;
    (void)block_scan_excl(v, sdat);
    if (threadIdx.x == 0) bsum[blockIdx.x] = sdat[255];
}

__global__ __launch_bounds__(1024) void k_scan2(const int* __restrict__ bsum,
                                                int* __restrict__ boffs,
                                                int* __restrict__ row_ptr,
                                                int nb, int n) {
    __shared__ int sdat[1024];
    int tid = threadIdx.x;
    int v = (tid < nb) ? bsum[tid] : 0;
    sdat[tid] = v;
    __syncthreads();
#pragma unroll
    for (int off = 1; off < 1024; off <<= 1) {
        int t = (tid >= off) ? sdat[tid - off] : 0;
        __syncthreads();
        sdat[tid] += t;
        __syncthreads();
    }
    if (tid < nb) boffs[tid] = sdat[tid] - v;
    if (tid == 0) row_ptr[n] = sdat[1023];
}

__global__ __launch_bounds__(256) void k_scan3(const int* __restrict__ cnt,
                                               const int* __restrict__ boffs,
                                               int* __restrict__ row_ptr,
                                               int* __restrict__ fill_pos, int n) {
    __shared__ int sdat[256];
    int i = blockIdx.x * 256 + threadIdx.x;
    int v = (i < n) ? cnt[i] : 0;
    int ex = block_scan_excl(v, sdat);
    if (i < n) {
        int rp = boffs[blockIdx.x] + ex;
        row_ptr[i] = rp;
        fill_pos[i] = rp;
    }
}

__global__ void k_fill(const int* __restrict__ ei, const int* __restrict__ cnt,
                       int* fill_pos, int2* __restrict__ er, int E, int n) {
    int t = blockIdx.x * blockDim.x + threadIdx.x;
    int total = E + n;
    if (t >= total) return;
    int s, d;
    if (t < E) { s = ei[t]; d = ei[E + t]; }
    else       { s = t - E; d = s; }
    float nrm = rsqrtf((float)cnt[s]) * rsqrtf((float)cnt[d]);
    int p = atomicAdd(&fill_pos[d], 1);
    er[p] = make_int2(s, __float_as_int(nrm));
}

// ------- W pre-pack into MFMA B-fragment order: Wp[((h*NCT+ct)*4+kt)*64 + l][r] -------
// B-frag layout (16x16x32): lane l supplies B[8*(l>>4)+r][l&15] of the K=32 x N=16 tile.
// h=0: bf16 hi part of W; h=1: bf16 lo residual.

template<int M>
__global__ void k_packW(const float* __restrict__ W, u16* __restrict__ Wp) {
    constexpr int NCT = M / 16;
    int t = blockIdx.x * blockDim.x + threadIdx.x;
    int total = 2 * NCT * 4 * 64;
    if (t >= total) return;
    int l  = t & 63;
    int q  = t >> 6;
    int kt = q & 3;
    int q2 = q >> 2;
    int ct = q2 % NCT;
    int h  = q2 / NCT;
    int col   = 16 * ct + (l & 15);
    int krow0 = 32 * kt + 8 * (l >> 4);
    u16* outp = Wp + (size_t)t * 8;
#pragma unroll
    for (int r = 0; r < 8; ++r) {
        float w  = W[(size_t)(krow0 + r) * M + col];
        u16 hi   = f2bf(w);
        u16 v    = (h == 0) ? hi : f2bf(w - bf2f(hi));
        outp[r] = v;
    }
}

// ------- MFMA GEMM: Y[n,M](bf16) = X[n,128](f32) @ W[128,M] via 3-term bf16 split ----

template<int M>
__global__ __launch_bounds__(256) void k_gemm_mfma(const float* __restrict__ X,
                                                   const u16* __restrict__ Wp,
                                                   u16* __restrict__ Y, int n) {
    constexpr int NCT = M / 16;
    constexpr int WPW = 2 * NCT * 4 * 64 * 8;  // u16 elements
    __shared__ u16 wlds[WPW];
    for (int i = threadIdx.x; i < WPW / 8; i += 256)
        ((uint4*)wlds)[i] = ((const uint4*)Wp)[i];
    __syncthreads();

    const int wid = threadIdx.x >> 6;
    const int l   = threadIdx.x & 63;
    const int lr  = l & 15;
    const int lg  = l >> 4;
    const int row0 = blockIdx.x * 64 + wid * 16;

    // A fragments (16 rows x K=128), split into hi/lo bf16
    bf16x8 ahi[4], alo[4];
    const int arow = row0 + lr;
    const bool rowok = arow < n;
    const float* xr = X + (size_t)arow * 128;
#pragma unroll
    for (int kt = 0; kt < 4; ++kt) {
        float v[8];
        if (rowok) {
            float4 p0 = *(const float4*)(xr + 32 * kt + 8 * lg);
            float4 p1 = *(const float4*)(xr + 32 * kt + 8 * lg + 4);
            v[0] = p0.x; v[1] = p0.y; v[2] = p0.z; v[3] = p0.w;
            v[4] = p1.x; v[5] = p1.y; v[6] = p1.z; v[7] = p1.w;
        } else {
#pragma unroll
            for (int r = 0; r < 8; ++r) v[r] = 0.f;
        }
#pragma unroll
        for (int r = 0; r < 8; ++r) {
            u16 hi = f2bf(v[r]);
            ahi[kt][r] = (short)hi;
            alo[kt][r] = (short)f2bf(v[r] - bf2f(hi));
        }
    }

#pragma unroll
    for (int ct = 0; ct < NCT; ++ct) {
        f32x4 acc = {0.f, 0.f, 0.f, 0.f};
        const u16* whi = wlds + (size_t)((0 * NCT + ct) * 4) * 512 + l * 8;
        const u16* wlo = wlds + (size_t)((1 * NCT + ct) * 4) * 512 + l * 8;
#pragma unroll
        for (int kt = 0; kt < 4; ++kt) {
            bf16x8 bh = *(const bf16x8*)(whi + kt * 512);
            bf16x8 bl = *(const bf16x8*)(wlo + kt * 512);
            acc = __builtin_amdgcn_mfma_f32_16x16x32_bf16(ahi[kt], bh, acc, 0, 0, 0);
            acc = __builtin_amdgcn_mfma_f32_16x16x32_bf16(alo[kt], bh, acc, 0, 0, 0);
            acc = __builtin_amdgcn_mfma_f32_16x16x32_bf16(ahi[kt], bl, acc, 0, 0, 0);
        }
        // D[4*lg+r][16*ct+lr]
#pragma unroll
        for (int r = 0; r < 4; ++r) {
            int row = row0 + lg * 4 + r;
            if (row < n) Y[(size_t)row * M + 16 * ct + lr] = f2bf(acc[r]);
        }
    }
}

// ------- CSR aggregation: out[d] = sum_e norm_e * h_bf16[src_e] (+bias, relu) -------

template<int F, bool RELU>
__global__ __launch_bounds__(256) void k_agg(const u16* __restrict__ h,
                                             const int* __restrict__ row_ptr,
                                             const int2* __restrict__ er,
                                             const float* __restrict__ bias,
                                             float* __restrict__ out, int n) {
    int node = blockIdx.x * 4 + (threadIdx.x >> 6);
    if (node >= n) return;
    int lane = threadIdx.x & 63;
    int beg = row_ptr[node], end = row_ptr[node + 1];
    if (F == 128) {
        const u16* hp = h + lane * 2;
        float ax0 = 0.f, ay0 = 0.f, ax1 = 0.f, ay1 = 0.f;
        float ax2 = 0.f, ay2 = 0.f, ax3 = 0.f, ay3 = 0.f;
        int e = beg;
        for (; e + 3 < end; e += 4) {
            int2 r0 = er[e], r1 = er[e + 1], r2 = er[e + 2], r3 = er[e + 3];
            ushort2 v0 = *(const ushort2*)(hp + (size_t)r0.x * 128);
            ushort2 v1 = *(const ushort2*)(hp + (size_t)r1.x * 128);
            ushort2 v2 = *(const ushort2*)(hp + (size_t)r2.x * 128);
            ushort2 v3 = *(const ushort2*)(hp + (size_t)r3.x * 128);
            float w0 = __int_as_float(r0.y), w1 = __int_as_float(r1.y);
            float w2 = __int_as_float(r2.y), w3 = __int_as_float(r3.y);
            ax0 += w0 * bf2f(v0.x); ay0 += w0 * bf2f(v0.y);
            ax1 += w1 * bf2f(v1.x); ay1 += w1 * bf2f(v1.y);
            ax2 += w2 * bf2f(v2.x); ay2 += w2 * bf2f(v2.y);
            ax3 += w3 * bf2f(v3.x); ay3 += w3 * bf2f(v3.y);
        }
        for (; e < end; ++e) {
            int2 r0 = er[e];
            float w0 = __int_as_float(r0.y);
            ushort2 v0 = *(const ushort2*)(hp + (size_t)r0.x * 128);
            ax0 += w0 * bf2f(v0.x); ay0 += w0 * bf2f(v0.y);
        }
        float ax = (ax0 + ax1) + (ax2 + ax3);
        float ay = (ay0 + ay1) + (ay2 + ay3);
        ax += bias[lane * 2]; ay += bias[lane * 2 + 1];
        if (RELU) { ax = fmaxf(ax, 0.f); ay = fmaxf(ay, 0.f); }
        f32x2 o; o.x = ax; o.y = ay;
        __builtin_nontemporal_store(o, (f32x2*)(out + (size_t)node * 128 + lane * 2));
    } else {
        const u16* hp = h + lane;
        float a0 = 0.f, a1 = 0.f, a2 = 0.f, a3 = 0.f;
        int e = beg;
        for (; e + 3 < end; e += 4) {
            int2 r0 = er[e], r1 = er[e + 1], r2 = er[e + 2], r3 = er[e + 3];
            u16 v0 = hp[(size_t)r0.x * 64];
            u16 v1 = hp[(size_t)r1.x * 64];
            u16 v2 = hp[(size_t)r2.x * 64];
            u16 v3 = hp[(size_t)r3.x * 64];
            a0 += __int_as_float(r0.y) * bf2f(v0);
            a1 += __int_as_float(r1.y) * bf2f(v1);
            a2 += __int_as_float(r2.y) * bf2f(v2);
            a3 += __int_as_float(r3.y) * bf2f(v3);
        }
        for (; e < end; ++e) {
            int2 r0 = er[e];
            a0 += __int_as_float(r0.y) * bf2f(hp[(size_t)r0.x * 64]);
        }
        float a = (a0 + a1) + (a2 + a3);
        a += bias[lane];
        if (RELU) a = fmaxf(a, 0.f);
        __builtin_nontemporal_store(a, out + (size_t)node * 64 + lane);
    }
}

// ---------------- launch ----------------

static inline char* alignp(char* p, size_t a) {
    return (char*)(((uintptr_t)p + a - 1) & ~(uintptr_t)(a - 1));
}

extern "C" void kernel_launch(void* const* d_in, const int* in_sizes, int n_in,
                              void* d_out, int out_size, void* d_ws, size_t ws_size,
                              hipStream_t stream) {
    const float* x  = (const float*)d_in[0];
    const int*   ei = (const int*)d_in[1];
    const float* W1 = (const float*)d_in[2];
    const float* b1 = (const float*)d_in[3];
    const float* W2 = (const float*)d_in[4];
    const float* b2 = (const float*)d_in[5];
    float* out = (float*)d_out;

    const int n  = in_sizes[0] / IN_F;
    const int E  = in_sizes[1] / 2;
    const int EN = E + n;
    const int nb = (n + 255) / 256;

    char* w = (char*)d_ws;
    int*   cnt      = (int*)w;   w = alignp(w + (size_t)n * 4, 256);
    int*   row_ptr  = (int*)w;   w = alignp(w + (size_t)(n + 1) * 4, 256);
    int*   fill_pos = (int*)w;   w = alignp(w + (size_t)n * 4, 256);
    int*   bsum     = (int*)w;   w = alignp(w + (size_t)nb * 4, 256);
    int*   boffs    = (int*)w;   w = alignp(w + (size_t)nb * 4, 256);
    int2*  er       = (int2*)w;  w = alignp(w + (size_t)EN * 8, 256);
    u16*   w1p      = (u16*)w;   w = alignp(w + (size_t)2 * 8 * 4 * 64 * 8 * 2, 256);
    u16*   w2p      = (u16*)w;   w = alignp(w + (size_t)2 * 4 * 4 * 64 * 8 * 2, 256);
    u16*   h1b      = (u16*)w;   w = alignp(w + (size_t)n * 128 * 2, 256);
    float* a1       = (float*)w; w = alignp(w + (size_t)n * 128 * 4, 256);
    u16*   h2b      = h1b;  // reuse: h1b dead after first aggregation

    k_init_cnt<<<nb, 256, 0, stream>>>(cnt, n);
    k_count<<<(E + 255) / 256, 256, 0, stream>>>(ei + E, cnt, E);
    k_scan1<<<nb, 256, 0, stream>>>(cnt, bsum, n);
    k_scan2<<<1, 1024, 0, stream>>>(bsum, boffs, row_ptr, nb, n);
    k_scan3<<<nb, 256, 0, stream>>>(cnt, boffs, row_ptr, fill_pos, n);
    k_fill<<<(EN + 255) / 256, 256, 0, stream>>>(ei, cnt, fill_pos, er, E, n);
    k_packW<128><<<(2 * 8 * 4 * 64 + 255) / 256, 256, 0, stream>>>(W1, w1p);
    k_packW<64><<<(2 * 4 * 4 * 64 + 255) / 256, 256, 0, stream>>>(W2, w2p);

    const int gb = (n + 63) / 64;
    k_gemm_mfma<128><<<gb, 256, 0, stream>>>(x, w1p, h1b, n);
    k_agg<128, true><<<(n + 3) / 4, 256, 0, stream>>>(h1b, row_ptr, er, b1, a1, n);
    k_gemm_mfma<64><<<gb, 256, 0, stream>>>(a1, w2p, h2b, n);
    k_agg<64, false><<<(n + 3) / 4, 256, 0, stream>>>(h2b, row_ptr, er, b2, out, n);
}